// Round 2
// baseline (295.903 us; speedup 1.0000x reference)
//
#include <hip/hip_runtime.h>
#include <math.h>

namespace {

constexpr int W_TS = 256, NE = 16, NB = 512, NI = 10, NF = 3;
constexpr int BI   = NB * NI;           // 5120
constexpr int PROJ = 7, INP = 4, EMB = 32, NTOT = 79;
constexpr int CPB  = 80;                // chains per block (8 (e,b) groups x 10 items)
constexpr int GPB  = 8;                 // (e,b) groups per block
constexpr int BLK  = CPB * 4;           // 320 threads = 5 waves
constexpr int PFK  = 8;                 // prefetch depth
constexpr float INV_SQRT_DEG = 0.70710678118654752440f;
constexpr size_t TS_IN  = (size_t)NE * BI * NF;   // 245760 floats / timestep
constexpr size_t TS_OUT = (size_t)NE * BI;        // 81920

// quad_perm DPP helper (pure-VALU cross-lane within each 4-lane quad)
template<int CTRL>
__device__ __forceinline__ float qp(float v) {
  return __int_as_float(
      __builtin_amdgcn_update_dpp(0, __float_as_int(v), CTRL, 0xF, 0xF, false));
}
// ctrl encodings: bcast lane0=0x00, lane1=0x55, lane2=0xAA, xor1=0xB1, xor2=0x4E

__device__ __forceinline__ float gelu_exact(float x) {
  return 0.5f * x * (1.0f + erff(x * 0.70710678118654752440f));
}

__global__ __launch_bounds__(BLK, 5)   // 5 waves/EU -> 4 blocks/CU -> all 1024 blocks resident
void ensemble_rnn(const float* __restrict__ xin,       // (W_TS,E,BI,F)
                  const float* __restrict__ h0,        // (E,BI)
                  const float* __restrict__ embedding, // (E,NB,EMB)
                  const float* __restrict__ w0g,       // (E,7,4)
                  const float* __restrict__ w1g,       // (E,7,4)
                  const float* __restrict__ b0g,       // (E,7)
                  const float* __restrict__ b1g,       // (E,7)
                  const float* __restrict__ wng,       // (E,1,7)
                  const float* __restrict__ bng,       // (E,1)
                  const float* __restrict__ damping,   // (E)
                  const float* __restrict__ hW_in,     // (E,32,32)
                  const float* __restrict__ hb_in,     // (E,32)
                  const float* __restrict__ hW_out,    // (E,79,32)
                  const float* __restrict__ hb_out,    // (E,79)
                  float* __restrict__ out)             // (W_TS,E,BI)
{
  // per-(group,lane) weight slice: w0s0[4] w0s1[4] w1s0[4] w1s1[4] b0s0 b0s1 b1s0 b1s1 wn0 wn1 pb
  __shared__ float sw[GPB * 4 * 23];
  const int tid = (int)threadIdx.x;
  const int e   = (int)blockIdx.x >> 6;            // 64 blocks per ensemble member

  if (tid < GPB * 4) {
    // ---------------- hypernetwork: one thread per (group, lane) ----------------
    const int g = tid >> 2, l = tid & 3;
    const int b = ((int)(blockIdx.x & 63)) * GPB + g;
    const int p1 = l + 4;
    const bool has1 = (p1 < PROJ);
    const int p1c = has1 ? p1 : 0;

    float emb[EMB];
    {
      const float4* ep =
          reinterpret_cast<const float4*>(embedding + ((size_t)e * NB + b) * EMB);
#pragma unroll
      for (int i = 0; i < EMB / 4; ++i) {
        float4 v = ep[i];
        emb[4*i+0] = v.x; emb[4*i+1] = v.y; emb[4*i+2] = v.z; emb[4*i+3] = v.w;
      }
    }
    float h1[EMB];
    {
      const float* Wi = hW_in + (size_t)e * EMB * EMB;
      const float* bb = hb_in + (size_t)e * EMB;
#pragma unroll
      for (int o = 0; o < EMB; ++o) {
        float acc = bb[o];
#pragma unroll
        for (int i = 0; i < EMB; ++i) acc = fmaf(Wi[o * EMB + i], emb[i], acc);
        h1[o] = gelu_exact(acc);
      }
    }
    const float* Wo = hW_out + (size_t)e * NTOT * EMB;
    const float* bo = hb_out + (size_t)e * NTOT;

#define ROWDOT(row, dst) do {                                   \
      float acc_ = bo[(row)];                                   \
      _Pragma("unroll")                                         \
      for (int i_ = 0; i_ < EMB; ++i_)                          \
        acc_ = fmaf(Wo[(row) * EMB + i_], h1[i_], acc_);        \
      (dst) = acc_;                                             \
    } while (0)

    float w0s0[4], w0s1[4], w1s0[4], w1s1[4];
#pragma unroll
    for (int i = 0; i < 4; ++i) { w0s0[i]=0.f; w0s1[i]=0.f; w1s0[i]=0.f; w1s1[i]=0.f; }
    float b0s0=0.f, b0s1=0.f, b1s0=0.f, b1s1=0.f, wn0=0.f, wn1=0.f, pb=0.f;

    // ---- w0 group: rows 0..27
    {
      float ss = 0.f;
#pragma unroll
      for (int p = 0; p < PROJ; ++p)
#pragma unroll
        for (int i = 0; i < INP; ++i) {
          float o; ROWDOT(p * INP + i, o);
          ss = fmaf(o, o, ss);
          if (p == l)  w0s0[i] = o;
          if (p == p1) w0s1[i] = o;
        }
      float rn = 0.f;
#pragma unroll
      for (int k = 0; k < PROJ * INP; ++k) { float w = w0g[e*28 + k]; rn = fmaf(w, w, rn); }
      float sc = fminf(fmaxf(sqrtf(rn) * 0.5f, 0.01f) / (sqrtf(ss) + 1e-8f), 1.0f);
#pragma unroll
      for (int i = 0; i < INP; ++i) {
        w0s0[i] = w0g[e*28 + l*INP + i] + w0s0[i] * sc;
        w0s1[i] = has1 ? (w0g[e*28 + p1c*INP + i] + w0s1[i] * sc) : 0.f;
      }
    }
    // ---- w1 group: rows 28..55
    {
      float ss = 0.f;
#pragma unroll
      for (int p = 0; p < PROJ; ++p)
#pragma unroll
        for (int i = 0; i < INP; ++i) {
          float o; ROWDOT(28 + p * INP + i, o);
          ss = fmaf(o, o, ss);
          if (p == l)  w1s0[i] = o;
          if (p == p1) w1s1[i] = o;
        }
      float rn = 0.f;
#pragma unroll
      for (int k = 0; k < PROJ * INP; ++k) { float w = w1g[e*28 + k]; rn = fmaf(w, w, rn); }
      float sc = fminf(fmaxf(sqrtf(rn) * 0.5f, 0.01f) / (sqrtf(ss) + 1e-8f), 1.0f);
#pragma unroll
      for (int i = 0; i < INP; ++i) {
        w1s0[i] = w1g[e*28 + l*INP + i] + w1s0[i] * sc;
        w1s1[i] = has1 ? (w1g[e*28 + p1c*INP + i] + w1s1[i] * sc) : 0.f;
      }
    }
    // ---- b0: rows 56..62, b1: 63..69, wn: 70..76
    {
      float ss = 0.f, r0 = 0.f, r1 = 0.f;
#pragma unroll
      for (int p = 0; p < PROJ; ++p) {
        float o; ROWDOT(56 + p, o);
        ss = fmaf(o, o, ss);
        if (p == l)  r0 = o;
        if (p == p1) r1 = o;
      }
      float rn = 0.f;
#pragma unroll
      for (int p = 0; p < PROJ; ++p) { float w = b0g[e*7 + p]; rn = fmaf(w, w, rn); }
      float sc = fminf(fmaxf(sqrtf(rn) * 0.5f, 0.01f) / (sqrtf(ss) + 1e-8f), 1.0f);
      b0s0 = b0g[e*7 + l] + r0 * sc;
      b0s1 = has1 ? (b0g[e*7 + p1c] + r1 * sc) : 0.f;
    }
    {
      float ss = 0.f, r0 = 0.f, r1 = 0.f;
#pragma unroll
      for (int p = 0; p < PROJ; ++p) {
        float o; ROWDOT(63 + p, o);
        ss = fmaf(o, o, ss);
        if (p == l)  r0 = o;
        if (p == p1) r1 = o;
      }
      float rn = 0.f;
#pragma unroll
      for (int p = 0; p < PROJ; ++p) { float w = b1g[e*7 + p]; rn = fmaf(w, w, rn); }
      float sc = fminf(fmaxf(sqrtf(rn) * 0.5f, 0.01f) / (sqrtf(ss) + 1e-8f), 1.0f);
      b1s0 = b1g[e*7 + l] + r0 * sc;
      b1s1 = has1 ? (b1g[e*7 + p1c] + r1 * sc) : 0.f;
    }
    {
      float ss = 0.f, r0 = 0.f, r1 = 0.f;
#pragma unroll
      for (int p = 0; p < PROJ; ++p) {
        float o; ROWDOT(70 + p, o);
        ss = fmaf(o, o, ss);
        if (p == l)  r0 = o;
        if (p == p1) r1 = o;
      }
      float rn = 0.f;
#pragma unroll
      for (int p = 0; p < PROJ; ++p) { float w = wng[e*7 + p]; rn = fmaf(w, w, rn); }
      float sc = fminf(fmaxf(sqrtf(rn) * 0.5f, 0.01f) / (sqrtf(ss) + 1e-8f), 1.0f);
      wn0 = (wng[e*7 + l] + r0 * sc) * INV_SQRT_DEG;
      wn1 = has1 ? ((wng[e*7 + p1c] + r1 * sc) * INV_SQRT_DEG) : 0.f;
    }
    // ---- bn: row 77 (row 78 unused by reference)
    {
      float o; ROWDOT(77, o);
      float ss = o * o;
      float w = bng[e];
      float rn = w * w;
      float sc = fminf(fmaxf(sqrtf(rn) * 0.5f, 0.01f) / (sqrtf(ss) + 1e-8f), 1.0f);
      float bne = w + o * sc;
      pb = (l == 3) ? bne : 0.f;
    }
#undef ROWDOT

    float* s = &sw[(g * 4 + l) * 23];
#pragma unroll
    for (int i = 0; i < 4; ++i) { s[i] = w0s0[i]; s[4+i] = w0s1[i]; s[8+i] = w1s0[i]; s[12+i] = w1s1[i]; }
    s[16] = b0s0; s[17] = b0s1; s[18] = b1s0; s[19] = b1s1;
    s[20] = wn0;  s[21] = wn1;  s[22] = pb;
  }

  __syncthreads();

  // ---------------- scan: 4 lanes per chain ----------------
  const unsigned c  = (unsigned)tid >> 2;     // chain within block, 0..79
  const unsigned l2 = (unsigned)tid & 3;
  const unsigned g2 = c / 10u;                // (e,b) group
  const float* s = &sw[(g2 * 4 + l2) * 23];
  float W00[4], W01[4], W10[4], W11[4];
#pragma unroll
  for (int i = 0; i < 4; ++i) { W00[i]=s[i]; W01[i]=s[4+i]; W10[i]=s[8+i]; W11[i]=s[12+i]; }
  const float B00=s[16], B01=s[17], B10=s[18], B11=s[19], WN0=s[20], WN1=s[21], PB=s[22];

  const float dec = 1.0f / (1.0f + expf(-damping[e]));
  const float omd = 1.0f - dec;

  const size_t cg = (size_t)blockIdx.x * CPB + c;      // global chain = e*BI + bi
  const float* xp = xin + cg * NF + (l2 < 3 ? l2 : 2); // lane3 dups x2 (value unused)
  float* op = out + cg;
  float h = h0[cg];

  float xb[PFK];
#pragma unroll
  for (int k = 0; k < PFK; ++k) xb[k] = xp[(size_t)k * TS_IN];

  const bool store_lane = (l2 == 0);

  for (int tc = 0; tc < W_TS; tc += PFK) {
#pragma unroll
    for (int k = 0; k < PFK; ++k) {
      const int t = tc + k;
      const float xv = xb[k];
      const int tn = t + PFK;
      if (tn < W_TS) xb[k] = xp[(size_t)tn * TS_IN];   // wave-uniform guard

      const float x0 = qp<0x00>(xv);   // broadcast quad-lane0
      const float x1 = qp<0x55>(xv);   // quad-lane1
      const float x2 = qp<0xAA>(xv);   // quad-lane2

      float a = B00;
      a = fmaf(W00[0], x0, a); a = fmaf(W00[1], x1, a);
      a = fmaf(W00[2], x2, a); a = fmaf(W00[3], h,  a);
      float cA = B10;
      cA = fmaf(W10[0], x0, cA); cA = fmaf(W10[1], x1, cA);
      cA = fmaf(W10[2], x2, cA); cA = fmaf(W10[3], h,  cA);
      float p = fmaf(WN0, a * cA, PB);

      float a1 = B01;
      a1 = fmaf(W01[0], x0, a1); a1 = fmaf(W01[1], x1, a1);
      a1 = fmaf(W01[2], x2, a1); a1 = fmaf(W01[3], h,  a1);
      float c1 = B11;
      c1 = fmaf(W11[0], x0, c1); c1 = fmaf(W11[1], x1, c1);
      c1 = fmaf(W11[2], x2, c1); c1 = fmaf(W11[3], h,  c1);
      p = fmaf(WN1, a1 * c1, p);

      p += qp<0xB1>(p);   // + lane^1
      p += qp<0x4E>(p);   // + lane^2  -> full quad sum in all lanes

      h = fmaf(h, omd, p);
      if (store_lane) op[(size_t)t * TS_OUT] = h;
    }
  }
}

} // anonymous namespace

extern "C" void kernel_launch(void* const* d_in, const int* in_sizes, int n_in,
                              void* d_out, int out_size, void* d_ws, size_t ws_size,
                              hipStream_t stream) {
  const float* xin  = (const float*)d_in[0];
  const float* h0   = (const float*)d_in[1];
  const float* emb  = (const float*)d_in[2];
  const float* w0   = (const float*)d_in[3];
  const float* w1   = (const float*)d_in[4];
  const float* b0   = (const float*)d_in[5];
  const float* b1   = (const float*)d_in[6];
  const float* wn   = (const float*)d_in[7];
  const float* bn   = (const float*)d_in[8];
  const float* damp = (const float*)d_in[9];
  const float* hWi  = (const float*)d_in[10];
  const float* hbi  = (const float*)d_in[11];
  const float* hWo  = (const float*)d_in[12];
  const float* hbo  = (const float*)d_in[13];
  float* out = (float*)d_out;

  dim3 grid(NE * BI / CPB);   // 1024 blocks
  dim3 block(BLK);            // 320 threads
  hipLaunchKernelGGL(ensemble_rnn, grid, block, 0, stream,
                     xin, h0, emb, w0, w1, b0, b1, wn, bn, damp,
                     hWi, hbi, hWo, hbo, out);
}

// Round 3
// 108.560 us; speedup vs baseline: 2.7257x; 2.7257x over previous
//
#include <hip/hip_runtime.h>
#include <math.h>

namespace {

constexpr int W_TS = 256, NE = 16, NB = 512, NI = 10, NF = 3;
constexpr int BI   = NB * NI;          // 5120
constexpr int PROJ = 7, IN_P = 4, EMB = 32, NTOT = 79;
constexpr int BLK  = 64;               // 1 wave/block -> 1280 blocks = 5 blocks/CU, balanced
constexpr int PFK  = 16;               // prefetch depth (W_TS % PFK == 0)
constexpr float MAX_RATIO    = 0.5f;
constexpr float INV_SQRT_DEG = 0.70710678118654752440f;
constexpr size_t TS_IN  = (size_t)NE * BI * NF;   // floats per timestep (input)
constexpr size_t TS_OUT = (size_t)NE * BI;        // floats per timestep (output)

__device__ __forceinline__ float gelu_exact(float x) {
  return 0.5f * x * (1.0f + erff(x * 0.70710678118654752440f));
}

template<int N, int OB>
__device__ __forceinline__ void constrain_group(
    const float* __restrict__ Wo, const float* __restrict__ bo,
    const float* __restrict__ h1, const float* __restrict__ refw,
    float* __restrict__ outw)
{
  float off[N];
  float ss = 0.f;
#pragma unroll
  for (int n = 0; n < N; ++n) {
    float acc = bo[OB + n];
#pragma unroll
    for (int i = 0; i < EMB; ++i)
      acc = fmaf(Wo[(OB + n) * EMB + i], h1[i], acc);
    off[n] = acc;
    ss = fmaf(acc, acc, ss);
  }
  float rn = 0.f;
#pragma unroll
  for (int n = 0; n < N; ++n) { float w = refw[n]; rn = fmaf(w, w, rn); }
  float max_norm = fmaxf(sqrtf(rn) * MAX_RATIO, 0.01f);
  float scale    = fminf(max_norm / (sqrtf(ss) + 1e-8f), 1.0f);
#pragma unroll
  for (int n = 0; n < N; ++n) outw[n] = refw[n] + off[n] * scale;
}

__global__ __launch_bounds__(BLK)
void ensemble_rnn(const float* __restrict__ xin,       // (W_TS,E,BI,F)
                  const float* __restrict__ h0,        // (E,BI)
                  const float* __restrict__ embedding, // (E,NB,EMB)
                  const float* __restrict__ w0g,       // (E,7,4)
                  const float* __restrict__ w1g,       // (E,7,4)
                  const float* __restrict__ b0g,       // (E,7)
                  const float* __restrict__ b1g,       // (E,7)
                  const float* __restrict__ wng,       // (E,1,7)
                  const float* __restrict__ bng,       // (E,1)
                  const float* __restrict__ damping,   // (E)
                  const float* __restrict__ hW_in,     // (E,32,32)
                  const float* __restrict__ hb_in,     // (E,32)
                  const float* __restrict__ hW_out,    // (E,79,32)
                  const float* __restrict__ hb_out,    // (E,79)
                  float* __restrict__ out)             // (W_TS,E,BI)
{
  constexpr int BLOCKS_PER_E = BI / BLK;  // 80 -> e block-uniform
  const int e  = (int)blockIdx.x / BLOCKS_PER_E;
  const int cg = (int)blockIdx.x * BLK + (int)threadIdx.x;  // = e*BI + bi
  const int bi = cg - e * BI;
  const int b  = bi / NI;

  // ---------------- hypernetwork (once per thread; identical to verified R1) ----
  float emb[EMB];
  {
    const float4* ep =
        reinterpret_cast<const float4*>(embedding + ((size_t)e * NB + b) * EMB);
#pragma unroll
    for (int i = 0; i < EMB / 4; ++i) {
      float4 v = ep[i];
      emb[4*i+0] = v.x; emb[4*i+1] = v.y; emb[4*i+2] = v.z; emb[4*i+3] = v.w;
    }
  }
  float h1[EMB];
  {
    const float* Wi = hW_in + (size_t)e * EMB * EMB;
    const float* bb = hb_in + (size_t)e * EMB;
#pragma unroll
    for (int o = 0; o < EMB; ++o) {
      float acc = bb[o];
#pragma unroll
      for (int i = 0; i < EMB; ++i) acc = fmaf(Wi[o * EMB + i], emb[i], acc);
      h1[o] = gelu_exact(acc);
    }
  }
  const float* Wo = hW_out + (size_t)e * NTOT * EMB;
  const float* bo = hb_out + (size_t)e * NTOT;

  float w0e[PROJ * IN_P], w1e[PROJ * IN_P];
  float b0e[PROJ], b1e[PROJ], wns[PROJ], bne;

  constrain_group<28, 0 >(Wo, bo, h1, w0g + e * 28, w0e);
  constrain_group<28, 28>(Wo, bo, h1, w1g + e * 28, w1e);
  constrain_group<7,  56>(Wo, bo, h1, b0g + e * 7,  b0e);
  constrain_group<7,  63>(Wo, bo, h1, b1g + e * 7,  b1e);
  constrain_group<7,  70>(Wo, bo, h1, wng + e * 7,  wns);
  constrain_group<1,  77>(Wo, bo, h1, bng + e,      &bne);

  const float dec = 1.0f / (1.0f + expf(-damping[e]));
  const float omd = 1.0f - dec;

  // ---------------- collapse to 5x5 quadratic form --------------------------
  // delta + omd*h = z5^T M z5  with z5=(x0,x1,x2,h,1), M = sum_o wn'_o w0h_o w1h_o^T
  // (+ bn in M44, + omd in the h*1 coefficient)
  float M[5][5];
#pragma unroll
  for (int i = 0; i < 5; ++i)
#pragma unroll
    for (int j = 0; j < 5; ++j) M[i][j] = 0.f;

#pragma unroll
  for (int o = 0; o < PROJ; ++o) {
    const float s = wns[o] * INV_SQRT_DEG;
    float w0h[5] = { w0e[o*4+0], w0e[o*4+1], w0e[o*4+2], w0e[o*4+3], b0e[o] };
    float w1h[5] = { w1e[o*4+0], w1e[o*4+1], w1e[o*4+2], w1e[o*4+3], b1e[o] };
#pragma unroll
    for (int i = 0; i < 5; ++i) {
      const float t = s * w0h[i];
#pragma unroll
      for (int j = 0; j < 5; ++j) M[i][j] = fmaf(t, w1h[j], M[i][j]);
    }
  }
  // symmetrized coefficients; c_ij = coeff of z_i*z_j (i<j), c_ii of z_i^2
  const float c00 = M[0][0];
  const float c01 = M[0][1] + M[1][0];
  const float c02 = M[0][2] + M[2][0];
  const float c03 = M[0][3] + M[3][0];
  const float c04 = M[0][4] + M[4][0];
  const float c11 = M[1][1];
  const float c12 = M[1][2] + M[2][1];
  const float c13 = M[1][3] + M[3][1];
  const float c14 = M[1][4] + M[4][1];
  const float c22 = M[2][2];
  const float c23 = M[2][3] + M[3][2];
  const float c24 = M[2][4] + M[4][2];
  const float c33 = M[3][3];
  const float c34 = M[3][4] + M[4][3] + omd;   // + leak term folded in
  const float c44 = M[4][4] + bne;             // + bias folded in

  // ---------------- RNN scan (hot loop) ----------------
  float h = h0[cg];
  const float* xbase = xin + (size_t)cg * NF;
  float* obase = out + cg;

  float xb[PFK][3];
#pragma unroll
  for (int k = 0; k < PFK; ++k) {
    const float* p = xbase + (size_t)k * TS_IN;
    xb[k][0] = p[0]; xb[k][1] = p[1]; xb[k][2] = p[2];   // merges to dwordx3
  }

#define STEP(T, K, DO_PF)                                          \
  do {                                                             \
    const float x0 = xb[K][0], x1 = xb[K][1], x2 = xb[K][2];       \
    if (DO_PF) {                                                   \
      const float* p = xbase + (size_t)((T) + PFK) * TS_IN;        \
      xb[K][0] = p[0]; xb[K][1] = p[1]; xb[K][2] = p[2];           \
    }                                                              \
    float r0 = fmaf(c00, x0, c04);                                 \
    r0 = fmaf(c01, x1, r0); r0 = fmaf(c02, x2, r0);                \
    r0 = fmaf(c03, h, r0);                                         \
    float r1 = fmaf(c11, x1, c14);                                 \
    r1 = fmaf(c12, x2, r1); r1 = fmaf(c13, h, r1);                 \
    float r2 = fmaf(c22, x2, c24); r2 = fmaf(c23, h, r2);          \
    float r3 = fmaf(c33, h, c34);                                  \
    float hn = c44;                                                \
    hn = fmaf(x0, r0, hn); hn = fmaf(x1, r1, hn);                  \
    hn = fmaf(x2, r2, hn); hn = fmaf(h, r3, hn);                   \
    h = hn;                                                        \
    obase[(size_t)(T) * TS_OUT] = h;                               \
  } while (0)

  int tc = 0;
  for (; tc < W_TS - PFK; tc += PFK) {
#pragma unroll
    for (int k = 0; k < PFK; ++k) STEP(tc + k, k, true);
  }
#pragma unroll
  for (int k = 0; k < PFK; ++k) STEP(tc + k, k, false);
#undef STEP
}

} // anonymous namespace

extern "C" void kernel_launch(void* const* d_in, const int* in_sizes, int n_in,
                              void* d_out, int out_size, void* d_ws, size_t ws_size,
                              hipStream_t stream) {
  const float* xin  = (const float*)d_in[0];
  const float* h0   = (const float*)d_in[1];
  const float* emb  = (const float*)d_in[2];
  const float* w0   = (const float*)d_in[3];
  const float* w1   = (const float*)d_in[4];
  const float* b0   = (const float*)d_in[5];
  const float* b1   = (const float*)d_in[6];
  const float* wn   = (const float*)d_in[7];
  const float* bn   = (const float*)d_in[8];
  const float* damp = (const float*)d_in[9];
  const float* hWi  = (const float*)d_in[10];
  const float* hbi  = (const float*)d_in[11];
  const float* hWo  = (const float*)d_in[12];
  const float* hbo  = (const float*)d_in[13];
  float* out = (float*)d_out;

  dim3 grid(NE * BI / BLK);   // 1280 blocks
  dim3 block(BLK);            // 64 threads = 1 wave
  hipLaunchKernelGGL(ensemble_rnn, grid, block, 0, stream,
                     xin, h0, emb, w0, w1, b0, b1, wn, bn, damp,
                     hWi, hbi, hWo, hbo, out);
}